// Round 2
// baseline (379.662 us; speedup 1.0000x reference)
//
#include <hip/hip_runtime.h>
#include <hip/hip_bf16.h>

// EncoderBlock: B=2, N=4096, D=256, H=8, HD=32, DFF=1024.
// Harness I/O dtype: fp32 (per reference). Internal compute: bf16 MFMA.
#define Bb 2
#define Nn 4096
#define Dd 256
#define Hh 8
#define HDh 32
#define DFFd 1024
#define MT (Bb*Nn)   // 8192 rows

typedef __attribute__((ext_vector_type(8))) short short8;
typedef __attribute__((ext_vector_type(4))) float f32x4;

__device__ __forceinline__ float bf2f(ushort u){
  union { unsigned int i; float f; } v; v.i = ((unsigned int)u) << 16; return v.f;
}
__device__ __forceinline__ ushort f2bf(float f){
  union { float f; unsigned int i; } v; v.f = f;
  unsigned int r = v.i + 0x7fffu + ((v.i >> 16) & 1u);
  return (ushort)(r >> 16);
}

// -------- fp32 weights -> bf16, concatenated [Wq|Wk|Wv|Wo|W1|W2] ------------
// sizes: 4 x 65536, then 262144, 262144  (total 786432 elems)
__global__ __launch_bounds__(256) void cvt_weights(
    const float* __restrict__ Wq, const float* __restrict__ Wk,
    const float* __restrict__ Wv, const float* __restrict__ Wo,
    const float* __restrict__ W1, const float* __restrict__ W2,
    ushort* __restrict__ out)
{
  const int base = (blockIdx.x * 256 + threadIdx.x) * 4;
  const float* src; int off;
  if (base < 262144) {
    const int w = base >> 16; off = base & 65535;
    src = (w == 0) ? Wq : (w == 1) ? Wk : (w == 2) ? Wv : Wo;
  } else if (base < 524288) { src = W1; off = base - 262144; }
  else                      { src = W2; off = base - 524288; }
  const float4 v = *(const float4*)(src + off);
  ushort4 o; o.x = f2bf(v.x); o.y = f2bf(v.y); o.z = f2bf(v.z); o.w = f2bf(v.w);
  *(ushort4*)(out + base) = o;
}

// -------- LayerNorm: (x-mean)/(std+1e-6); fp32 in, bf16 out; wave per row ---
__global__ __launch_bounds__(256) void ln_kernel(const float* __restrict__ x,
                                                 ushort* __restrict__ out)
{
  const int wave = threadIdx.x >> 6, lane = threadIdx.x & 63;
  const int row = blockIdx.x * 4 + wave;
  const float4 u = *(const float4*)(x + (size_t)row * Dd + lane * 4);
  float s1 = u.x + u.y + u.z + u.w;
  float s2 = u.x*u.x + u.y*u.y + u.z*u.z + u.w*u.w;
  #pragma unroll
  for (int m = 1; m < 64; m <<= 1) { s1 += __shfl_xor(s1, m, 64); s2 += __shfl_xor(s2, m, 64); }
  const float mean = s1 * (1.0f / Dd);
  float var = s2 * (1.0f / Dd) - mean * mean;
  var = var < 0.f ? 0.f : var;
  const float inv = 1.0f / (sqrtf(var) + 1e-6f);
  ushort4 o;
  o.x = f2bf((u.x - mean) * inv); o.y = f2bf((u.y - mean) * inv);
  o.z = f2bf((u.z - mean) * inv); o.w = f2bf((u.w - mean) * inv);
  *(ushort4*)(out + (size_t)row * Dd + lane * 4) = o;
}

// -------- 64x64-tile MFMA GEMM, C = A[MxK](bf16) @ B[KxN](bf16) + bias(f32) -
// EPI 0: scatter bf16 to head layout [B,H,N,HD]        (QKV projections)
// EPI 1: + fp32 residual, fp32 row-major out           (Wo proj, final W2)
// EPI 2: gelu(tanh approx), bf16 row-major out         (W1)
template<int EPI>
__global__ __launch_bounds__(256) void gemm_epi(
    const ushort* __restrict__ A, const ushort* __restrict__ Bw,
    const float* __restrict__ bias, const void* __restrict__ resv,
    void* __restrict__ outv, int M, int N, int K)
{
  __shared__ __align__(16) ushort As[64][40];   // row-major A tile
  __shared__ __align__(16) ushort Bt[64][40];   // B tile transposed: Bt[n][k]
  const int tid = threadIdx.x;
  const int wave = tid >> 6, lane = tid & 63;
  const int quad = lane >> 4, l15 = lane & 15;
  const int m0 = blockIdx.y * 64, n0 = blockIdx.x * 64;
  f32x4 acc[4];
  #pragma unroll
  for (int i = 0; i < 4; i++) acc[i] = (f32x4){0.f, 0.f, 0.f, 0.f};
  const int ar = tid >> 2, ac = (tid & 3) * 8;   // A stage: 16B per thread
  const int bk = tid >> 3, bn = tid & 7;         // B stage: strided cols
  for (int k0 = 0; k0 < K; k0 += 32) {
    __syncthreads();
    *(int4*)(&As[ar][ac]) = *(const int4*)(A + (size_t)(m0 + ar) * K + (k0 + ac));
    const ushort* bp = Bw + (size_t)(k0 + bk) * N + n0 + bn;
    #pragma unroll
    for (int j = 0; j < 8; j++) Bt[bn + 8 * j][bk] = bp[8 * j];
    __syncthreads();
    const short8 af = *(const short8*)(&As[wave * 16 + l15][quad * 8]);
    #pragma unroll
    for (int nt = 0; nt < 4; nt++) {
      const short8 bf = *(const short8*)(&Bt[nt * 16 + l15][quad * 8]);
      acc[nt] = __builtin_amdgcn_mfma_f32_16x16x32_bf16(af, bf, acc[nt], 0, 0, 0);
    }
  }
  const int row_base = m0 + wave * 16 + quad * 4;
  #pragma unroll
  for (int nt = 0; nt < 4; nt++) {
    const int col = n0 + nt * 16 + l15;
    const float bv = bias[col];
    #pragma unroll
    for (int i = 0; i < 4; i++) {
      const int row = row_base + i;
      float c = acc[nt][i] + bv;
      if (EPI == 0) {
        ushort* out = (ushort*)outv;
        const int b = row >> 12, n = row & (Nn - 1);
        const int h = col >> 5, hd = col & 31;
        out[((size_t)(b * Hh + h) * Nn + n) * HDh + hd] = f2bf(c);
      } else if (EPI == 1) {
        const float* res = (const float*)resv;
        float* out = (float*)outv;
        const size_t idx = (size_t)row * N + col;
        out[idx] = c + res[idx];
      } else {
        ushort* out = (ushort*)outv;
        const float t = tanhf(0.7978845608028654f * (c + 0.044715f * c * c * c));
        out[(size_t)row * N + col] = f2bf(0.5f * c * (1.0f + t));
      }
    }
  }
}

// -------- Flash attention: per (b,h) x 64-row q-tile, kv tiles of 64 --------
__global__ __launch_bounds__(256) void attn_kernel(
    const ushort* __restrict__ qp, const ushort* __restrict__ kp,
    const ushort* __restrict__ vp, ushort* __restrict__ out)
{
  __shared__ __align__(16) ushort Ks[64][40];      // K tile row-major [kv][d]
  __shared__ __align__(16) ushort Vt[32][72];      // V tile transposed [d][kv]
  __shared__ __align__(16) ushort Ps[4][16][72];   // per-wave P round-trip
  const int tid = threadIdx.x;
  const int wave = tid >> 6, lane = tid & 63;
  const int quad = lane >> 4, l15 = lane & 15;
  const int bh = blockIdx.y, qt = blockIdx.x;
  const size_t base = (size_t)bh * Nn * HDh;
  const int qrow = qt * 64 + wave * 16 + l15;
  const short8 qf = *(const short8*)(qp + base + (size_t)qrow * HDh + quad * 8);
  f32x4 o0 = {0.f,0.f,0.f,0.f}, o1 = {0.f,0.f,0.f,0.f};
  float m_i[4], l_i[4];
  #pragma unroll
  for (int i = 0; i < 4; i++) { m_i[i] = -1e30f; l_i[i] = 0.f; }
  const float c1 = 1.4426950408889634f * 0.17677669529663687f;  // log2(e)/sqrt(32)
  const int kr = tid >> 2, kc = (tid & 3) * 8;
  const int vd = tid & 3, vr = tid >> 2;
  for (int kv0 = 0; kv0 < Nn; kv0 += 64) {
    __syncthreads();
    *(int4*)(&Ks[kr][kc]) = *(const int4*)(kp + base + (size_t)(kv0 + kr) * HDh + kc);
    const ushort* vrow = vp + base + (size_t)(kv0 + vr) * HDh;
    #pragma unroll
    for (int j = 0; j < 8; j++) Vt[vd + 4 * j][vr] = vrow[vd + 4 * j];
    __syncthreads();
    // S = Q K^T (16 q-rows per wave x 64 kv)
    f32x4 s[4];
    #pragma unroll
    for (int nt = 0; nt < 4; nt++) {
      const short8 kf = *(const short8*)(&Ks[nt * 16 + l15][quad * 8]);
      f32x4 z = {0.f,0.f,0.f,0.f};
      s[nt] = __builtin_amdgcn_mfma_f32_16x16x32_bf16(qf, kf, z, 0, 0, 0);
    }
    // online softmax in log2 domain: p = exp2(s*c1 - m')
    float mnew[4], alpha[4], rs[4];
    #pragma unroll
    for (int i = 0; i < 4; i++) {
      float mx = fmaxf(fmaxf(s[0][i], s[1][i]), fmaxf(s[2][i], s[3][i])) * c1;
      #pragma unroll
      for (int m = 1; m < 16; m <<= 1) mx = fmaxf(mx, __shfl_xor(mx, m, 64));
      mnew[i] = fmaxf(m_i[i], mx);
      alpha[i] = exp2f(m_i[i] - mnew[i]);
      m_i[i] = mnew[i];
      rs[i] = 0.f;
    }
    #pragma unroll
    for (int nt = 0; nt < 4; nt++) {
      #pragma unroll
      for (int i = 0; i < 4; i++) {
        const float p = exp2f(fmaf(s[nt][i], c1, -mnew[i]));
        rs[i] += p;
        Ps[wave][quad * 4 + i][nt * 16 + l15] = f2bf(p);
      }
    }
    #pragma unroll
    for (int i = 0; i < 4; i++) {
      #pragma unroll
      for (int m = 1; m < 16; m <<= 1) rs[i] += __shfl_xor(rs[i], m, 64);
      l_i[i] = l_i[i] * alpha[i] + rs[i];
      o0[i] *= alpha[i];
      o1[i] *= alpha[i];
    }
    __syncthreads();
    // O += P @ V
    #pragma unroll
    for (int ss = 0; ss < 2; ss++) {
      const short8 af = *(const short8*)(&Ps[wave][l15][ss * 32 + quad * 8]);
      const short8 b0 = *(const short8*)(&Vt[l15][ss * 32 + quad * 8]);
      const short8 b1 = *(const short8*)(&Vt[16 + l15][ss * 32 + quad * 8]);
      o0 = __builtin_amdgcn_mfma_f32_16x16x32_bf16(af, b0, o0, 0, 0, 0);
      o1 = __builtin_amdgcn_mfma_f32_16x16x32_bf16(af, b1, o1, 0, 0, 0);
    }
  }
  const int b = bh >> 3, h = bh & 7;
  #pragma unroll
  for (int i = 0; i < 4; i++) {
    const int n = qt * 64 + wave * 16 + quad * 4 + i;
    const float inv = 1.0f / l_i[i];
    const size_t ro = ((size_t)(b * Nn + n)) * Dd + h * HDh;
    out[ro + l15] = f2bf(o0[i] * inv);
    out[ro + 16 + l15] = f2bf(o1[i] * inv);
  }
}

extern "C" void kernel_launch(void* const* d_in, const int* in_sizes, int n_in,
                              void* d_out, int out_size, void* d_ws, size_t ws_size,
                              hipStream_t stream)
{
  const float* x  = (const float*)d_in[0];
  const float* Wq = (const float*)d_in[1];
  const float* bq = (const float*)d_in[2];
  const float* Wk = (const float*)d_in[3];
  const float* bk = (const float*)d_in[4];
  const float* Wv = (const float*)d_in[5];
  const float* bv = (const float*)d_in[6];
  const float* Wo = (const float*)d_in[7];
  const float* bo = (const float*)d_in[8];
  const float* W1 = (const float*)d_in[9];
  const float* b1 = (const float*)d_in[10];
  const float* W2 = (const float*)d_in[11];
  const float* b2 = (const float*)d_in[12];

  char* ws = (char*)d_ws;
  const size_t T  = (size_t)MT * Dd;              // 2,097,152 elems
  const size_t WB = 786432;                       // total weight elems (bf16)
  // byte layout (all 16B-aligned):
  ushort* wb  = (ushort*)ws;                      // [Wq|Wk|Wv|Wo|W1|W2] bf16
  ushort* s0  = (ushort*)(ws + WB * 2);           // 4 MiB slots
  ushort* s1  = s0 + T;
  ushort* s2  = s1 + T;
  ushort* s3  = s2 + T;
  float*  xsk = (float*)(s3 + T);                 // fp32, 8 MiB
  ushort* xn2 = (ushort*)(xsk + T);               // bf16, 4 MiB
  // aliases per lifetime:
  ushort* xn1  = s0;        // LN1 out; dead after V proj
  ushort* qb   = s1;
  ushort* kb   = s2;
  ushort* vb   = s3;
  ushort* attn = s0;        // reuse xn1 slot; dead after Wo
  ushort* hid  = s0;        // [M,DFF] bf16 = 16 MiB, spans s0..s3 (all dead)
  float*  outp = (float*)d_out;

  ushort* wqb = wb;
  ushort* wkb = wb + 65536;
  ushort* wvb = wb + 131072;
  ushort* wob = wb + 196608;
  ushort* w1b = wb + 262144;
  ushort* w2b = wb + 524288;

  const dim3 blk(256);
  hipLaunchKernelGGL(cvt_weights, dim3(768), blk, 0, stream, Wq, Wk, Wv, Wo, W1, W2, wb);
  hipLaunchKernelGGL(ln_kernel, dim3(MT / 4), blk, 0, stream, x, xn1);

  const dim3 gD(Dd / 64, MT / 64);      // (4,128)
  hipLaunchKernelGGL((gemm_epi<0>), gD, blk, 0, stream, xn1, wqb, bq, (const void*)nullptr, (void*)qb, MT, Dd, Dd);
  hipLaunchKernelGGL((gemm_epi<0>), gD, blk, 0, stream, xn1, wkb, bk, (const void*)nullptr, (void*)kb, MT, Dd, Dd);
  hipLaunchKernelGGL((gemm_epi<0>), gD, blk, 0, stream, xn1, wvb, bv, (const void*)nullptr, (void*)vb, MT, Dd, Dd);

  hipLaunchKernelGGL(attn_kernel, dim3(Nn / 64, Bb * Hh), blk, 0, stream, qb, kb, vb, attn);

  hipLaunchKernelGGL((gemm_epi<1>), gD, blk, 0, stream, attn, wob, bo, (const void*)x, (void*)xsk, MT, Dd, Dd);
  hipLaunchKernelGGL(ln_kernel, dim3(MT / 4), blk, 0, stream, xsk, xn2);

  const dim3 gF(DFFd / 64, MT / 64);    // (16,128)
  hipLaunchKernelGGL((gemm_epi<2>), gF, blk, 0, stream, xn2, w1b, b1, (const void*)nullptr, (void*)hid, MT, DFFd, Dd);
  hipLaunchKernelGGL((gemm_epi<1>), gD, blk, 0, stream, hid, w2b, b2, (const void*)xsk, (void*)outp, MT, Dd, DFFd);
}

// Round 3
// 286.888 us; speedup vs baseline: 1.3234x; 1.3234x over previous
//
#include <hip/hip_runtime.h>
#include <hip/hip_bf16.h>

// EncoderBlock: B=2, N=4096, D=256, H=8, HD=32, DFF=1024.
// I/O fp32; internal bf16 MFMA. Attention computes S^T/O^T (column softmax).
#define Bb 2
#define Nn 4096
#define Dd 256
#define Hh 8
#define HDh 32
#define DFFd 1024
#define MT (Bb*Nn)   // 8192 rows
#define Tt ((size_t)MT * Dd)

typedef __attribute__((ext_vector_type(8))) short short8;
typedef __attribute__((ext_vector_type(4))) float f32x4;

__device__ __forceinline__ float bf2f(ushort u){
  union { unsigned int i; float f; } v; v.i = ((unsigned int)u) << 16; return v.f;
}
__device__ __forceinline__ ushort f2bf(float f){           // RNE
  union { float f; unsigned int i; } v; v.f = f;
  unsigned int r = v.i + 0x7fffu + ((v.i >> 16) & 1u);
  return (ushort)(r >> 16);
}
__device__ __forceinline__ ushort f2bff(float f){          // fast round (p>=0)
  union { float f; unsigned int i; } v; v.f = f;
  return (ushort)((v.i + 0x8000u) >> 16);
}

// ---- prep: fp32 weights -> bf16 transposed WT[n][k]; concat qkv bias -------
// wt layout: WTqkv[768][256] | WTo[256][256] | WT1[1024][256] | WT2[256][1024]
__global__ __launch_bounds__(256) void prep_kernel(
    const float* __restrict__ Wq, const float* __restrict__ Wk,
    const float* __restrict__ Wv, const float* __restrict__ Wo,
    const float* __restrict__ W1, const float* __restrict__ W2,
    const float* __restrict__ bq, const float* __restrict__ bk,
    const float* __restrict__ bv, ushort* __restrict__ wt,
    float* __restrict__ bqkv)
{
  if (blockIdx.x == 768) {
    const int t = threadIdx.x;
    bqkv[t] = bq[t]; bqkv[256 + t] = bk[t]; bqkv[512 + t] = bv[t];
    return;
  }
  const int base = (blockIdx.x * 256 + threadIdx.x) * 4;   // [0, 786432)
  const float* src; int k0, Ns;
  if (base < 196608) {                       // WTqkv, K=256
    const int n = base >> 8; k0 = base & 255;
    const int w = n >> 8, cn = n & 255;
    src = (w == 0 ? Wq : w == 1 ? Wk : Wv) + cn; Ns = 256;
  } else if (base < 262144) {                // WTo, K=256
    const int off = base - 196608;
    src = Wo + (off >> 8); k0 = off & 255; Ns = 256;
  } else if (base < 524288) {                // WT1, K=256
    const int off = base - 262144;
    src = W1 + (off >> 8); k0 = off & 255; Ns = 1024;
  } else {                                   // WT2, K=1024
    const int off = base - 524288;
    src = W2 + (off >> 10); k0 = off & 1023; Ns = 256;
  }
  ushort4 o;
  o.x = f2bf(src[(size_t)(k0 + 0) * Ns]);
  o.y = f2bf(src[(size_t)(k0 + 1) * Ns]);
  o.z = f2bf(src[(size_t)(k0 + 2) * Ns]);
  o.w = f2bf(src[(size_t)(k0 + 3) * Ns]);
  *(ushort4*)(wt + base) = o;
}

// ---- LayerNorm: (x-mean)/(std+1e-6); fp32 in, bf16 out; wave per row -------
__global__ __launch_bounds__(256) void ln_kernel(const float* __restrict__ x,
                                                 ushort* __restrict__ out)
{
  const int wave = threadIdx.x >> 6, lane = threadIdx.x & 63;
  const int row = blockIdx.x * 4 + wave;
  const float4 u = *(const float4*)(x + (size_t)row * Dd + lane * 4);
  float s1 = u.x + u.y + u.z + u.w;
  float s2 = u.x*u.x + u.y*u.y + u.z*u.z + u.w*u.w;
  #pragma unroll
  for (int m = 1; m < 64; m <<= 1) { s1 += __shfl_xor(s1, m, 64); s2 += __shfl_xor(s2, m, 64); }
  const float mean = s1 * (1.0f / Dd);
  float var = s2 * (1.0f / Dd) - mean * mean;
  var = var < 0.f ? 0.f : var;
  const float inv = 1.0f / (sqrtf(var) + 1e-6f);
  ushort4 o;
  o.x = f2bf((u.x - mean) * inv); o.y = f2bf((u.y - mean) * inv);
  o.z = f2bf((u.z - mean) * inv); o.w = f2bf((u.w - mean) * inv);
  *(ushort4*)(out + (size_t)row * Dd + lane * 4) = o;
}

// ---- 128x64-tile MFMA GEMM: C = A[8192xK] @ B[KxN] + bias; BT[n][k] input --
// EPI 0: scatter bf16 to [B,H,N,HD] x3 (fused QKV, N=768)
// EPI 1: + fp32 residual, fp32 out
// EPI 2: gelu(tanh), bf16 out
template<int EPI>
__global__ __launch_bounds__(256) void gemm_epi(
    const ushort* __restrict__ A, const ushort* __restrict__ BT,
    const float* __restrict__ bias, const void* __restrict__ resv,
    void* __restrict__ outv, int N, int K)
{
  __shared__ __align__(16) ushort As[128][40];
  __shared__ __align__(16) ushort Bs[64][40];
  const int tid = threadIdx.x;
  const int wave = tid >> 6, lane = tid & 63;
  const int quad = lane >> 4, l15 = lane & 15;
  const int m0 = blockIdx.y * 128, n0 = blockIdx.x * 64;
  f32x4 acc[2][4];
  #pragma unroll
  for (int mt = 0; mt < 2; mt++)
    #pragma unroll
    for (int nt = 0; nt < 4; nt++) acc[mt][nt] = (f32x4){0.f,0.f,0.f,0.f};
  const int sr = tid >> 2, sc = (tid & 3) * 8;
  const ushort* Arow0 = A + (size_t)(m0 + sr) * K + sc;
  const ushort* Arow1 = A + (size_t)(m0 + 64 + sr) * K + sc;
  const ushort* Brow  = BT + (size_t)(n0 + sr) * K + sc;
  for (int k0 = 0; k0 < K; k0 += 32) {
    __syncthreads();
    *(int4*)(&As[sr][sc])      = *(const int4*)(Arow0 + k0);
    *(int4*)(&As[64 + sr][sc]) = *(const int4*)(Arow1 + k0);
    *(int4*)(&Bs[sr][sc])      = *(const int4*)(Brow + k0);
    __syncthreads();
    short8 af0 = *(const short8*)(&As[wave * 32 + l15][quad * 8]);
    short8 af1 = *(const short8*)(&As[wave * 32 + 16 + l15][quad * 8]);
    #pragma unroll
    for (int nt = 0; nt < 4; nt++) {
      const short8 bf = *(const short8*)(&Bs[nt * 16 + l15][quad * 8]);
      acc[0][nt] = __builtin_amdgcn_mfma_f32_16x16x32_bf16(af0, bf, acc[0][nt], 0, 0, 0);
      acc[1][nt] = __builtin_amdgcn_mfma_f32_16x16x32_bf16(af1, bf, acc[1][nt], 0, 0, 0);
    }
  }
  #pragma unroll
  for (int mt = 0; mt < 2; mt++) {
    const int row0 = m0 + wave * 32 + mt * 16 + quad * 4;
    #pragma unroll
    for (int nt = 0; nt < 4; nt++) {
      const int col = n0 + nt * 16 + l15;
      const float bv = bias[col];
      #pragma unroll
      for (int i = 0; i < 4; i++) {
        const int row = row0 + i;
        float c = acc[mt][nt][i] + bv;
        if (EPI == 0) {
          ushort* qkv = (ushort*)outv;
          const int w = n0 >> 8;
          const int cd = (n0 & 255) + nt * 16 + l15;
          const int h = cd >> 5, hd = cd & 31;
          const int b = row >> 12, n = row & (Nn - 1);
          qkv[(size_t)w * Tt + ((size_t)((b * Hh + h) * Nn + n)) * HDh + hd] = f2bf(c);
        } else if (EPI == 1) {
          const float* res = (const float*)resv;
          float* out = (float*)outv;
          const size_t idx = (size_t)row * N + col;
          out[idx] = c + res[idx];
        } else {
          ushort* out = (ushort*)outv;
          const float t = tanhf(0.7978845608028654f * (c + 0.044715f * c * c * c));
          out[(size_t)row * N + col] = f2bf(0.5f * c * (1.0f + t));
        }
      }
    }
  }
}

// ---- Flash attention, transposed: S^T = K Q^T, column softmax, O^T = V^T P^T
__global__ __launch_bounds__(256) void attn_kernel(
    const ushort* __restrict__ qp, const ushort* __restrict__ kp,
    const ushort* __restrict__ vp, ushort* __restrict__ out)
{
  __shared__ __align__(16) ushort Ks[64][40];      // K tile [kv][d] (reused for O epilogue)
  __shared__ __align__(16) ushort Vt[32][80];      // V^T tile [d][kv]
  __shared__ __align__(16) ushort Ps[4][16][72];   // per-wave P^T as [q][kv]
  const int tid = threadIdx.x;
  const int wave = tid >> 6, lane = tid & 63;
  const int quad = lane >> 4, l15 = lane & 15;
  const int bh = blockIdx.y, qt = blockIdx.x;
  const size_t base = (size_t)bh * Nn * HDh;
  const int qrow = qt * 64 + wave * 16 + l15;
  const short8 qf = *(const short8*)(qp + base + (size_t)qrow * HDh + quad * 8);
  f32x4 o0 = {0.f,0.f,0.f,0.f}, o1 = {0.f,0.f,0.f,0.f};   // O^T: d=quad*4+i (+16), q=l15
  float m_i = -1e30f, l_i = 0.f;                           // per q-column
  const float c1 = 1.4426950408889634f * 0.17677669529663687f;  // log2(e)/sqrt(32)
  const int kr = tid >> 2, kc = (tid & 3) * 8;
  const int vd = tid & 3, vr = tid >> 2;
  for (int kv0 = 0; kv0 < Nn; kv0 += 64) {
    __syncthreads();
    *(int4*)(&Ks[kr][kc]) = *(const int4*)(kp + base + (size_t)(kv0 + kr) * HDh + kc);
    const ushort* vrow = vp + base + (size_t)(kv0 + vr) * HDh;
    #pragma unroll
    for (int j = 0; j < 8; j++) Vt[vd + 4 * j][vr] = vrow[vd + 4 * j];
    __syncthreads();
    // S^T[kv=nt*16+quad*4+i][q=l15]
    f32x4 s[4];
    #pragma unroll
    for (int nt = 0; nt < 4; nt++) {
      const short8 kf = *(const short8*)(&Ks[nt * 16 + l15][quad * 8]);
      s[nt] = __builtin_amdgcn_mfma_f32_16x16x32_bf16(kf, qf, (f32x4){0.f,0.f,0.f,0.f}, 0, 0, 0);
    }
    // column softmax: in-lane over 16 regs + 2 cross-quad shuffles
    float mx = s[0][0];
    #pragma unroll
    for (int nt = 0; nt < 4; nt++)
      #pragma unroll
      for (int i = 0; i < 4; i++) mx = fmaxf(mx, s[nt][i]);
    mx *= c1;
    mx = fmaxf(mx, __shfl_xor(mx, 16, 64));
    mx = fmaxf(mx, __shfl_xor(mx, 32, 64));
    const float mnew = fmaxf(m_i, mx);
    const float alpha = __builtin_amdgcn_exp2f(m_i - mnew);
    m_i = mnew;
    float rs = 0.f;
    #pragma unroll
    for (int nt = 0; nt < 4; nt++) {
      const float p0 = __builtin_amdgcn_exp2f(fmaf(s[nt][0], c1, -mnew));
      const float p1 = __builtin_amdgcn_exp2f(fmaf(s[nt][1], c1, -mnew));
      const float p2 = __builtin_amdgcn_exp2f(fmaf(s[nt][2], c1, -mnew));
      const float p3 = __builtin_amdgcn_exp2f(fmaf(s[nt][3], c1, -mnew));
      rs += (p0 + p1) + (p2 + p3);
      ushort4 pk;
      pk.x = f2bff(p0); pk.y = f2bff(p1); pk.z = f2bff(p2); pk.w = f2bff(p3);
      *(ushort4*)(&Ps[wave][l15][nt * 16 + quad * 4]) = pk;   // P^T[q][kv], b64
    }
    rs += __shfl_xor(rs, 16, 64);
    rs += __shfl_xor(rs, 32, 64);
    l_i = l_i * alpha + rs;
    #pragma unroll
    for (int i = 0; i < 4; i++) { o0[i] *= alpha; o1[i] *= alpha; }
    __builtin_amdgcn_wave_barrier();   // Ps is wave-local; DS ops in-order per wave
    #pragma unroll
    for (int ks = 0; ks < 2; ks++) {
      const short8 pf = *(const short8*)(&Ps[wave][l15][ks * 32 + quad * 8]);
      const short8 v0 = *(const short8*)(&Vt[l15][ks * 32 + quad * 8]);
      const short8 v1 = *(const short8*)(&Vt[16 + l15][ks * 32 + quad * 8]);
      o0 = __builtin_amdgcn_mfma_f32_16x16x32_bf16(v0, pf, o0, 0, 0, 0);
      o1 = __builtin_amdgcn_mfma_f32_16x16x32_bf16(v1, pf, o1, 0, 0, 0);
    }
    __builtin_amdgcn_wave_barrier();
  }
  // epilogue: transpose O^T -> O rows via reused Ks, coalesced 16B stores
  __syncthreads();   // protect Ks against waves still in final S^T
  const float inv = 1.0f / l_i;
  #pragma unroll
  for (int i = 0; i < 4; i++) {
    Ks[wave * 16 + l15][quad * 4 + i]      = f2bff(o0[i] * inv);
    Ks[wave * 16 + l15][16 + quad * 4 + i] = f2bff(o1[i] * inv);
  }
  __builtin_amdgcn_wave_barrier();
  const int rq = lane >> 2, c4 = lane & 3;
  const short8 ov = *(const short8*)(&Ks[wave * 16 + rq][c4 * 8]);
  const int b = bh >> 3, h = bh & 7;
  const int n = qt * 64 + wave * 16 + rq;
  *(short8*)(out + ((size_t)(b * Nn + n)) * Dd + h * HDh + c4 * 8) = ov;
}

extern "C" void kernel_launch(void* const* d_in, const int* in_sizes, int n_in,
                              void* d_out, int out_size, void* d_ws, size_t ws_size,
                              hipStream_t stream)
{
  const float* x  = (const float*)d_in[0];
  const float* Wq = (const float*)d_in[1];
  const float* bq = (const float*)d_in[2];
  const float* Wk = (const float*)d_in[3];
  const float* bk = (const float*)d_in[4];
  const float* Wv = (const float*)d_in[5];
  const float* bv = (const float*)d_in[6];
  const float* Wo = (const float*)d_in[7];
  const float* bo = (const float*)d_in[8];
  const float* W1 = (const float*)d_in[9];
  const float* b1 = (const float*)d_in[10];
  const float* W2 = (const float*)d_in[11];
  const float* b2 = (const float*)d_in[12];

  char* ws = (char*)d_ws;
  ushort* wt    = (ushort*)ws;                       // 786432 bf16 = 1.5 MiB
  ushort* wtqkv = wt;
  ushort* wto   = wt + 196608;
  ushort* wt1   = wt + 262144;
  ushort* wt2   = wt + 524288;
  float*  bqkv  = (float*)(ws + 786432 * 2);         // 768 fp32
  ushort* s0    = (ushort*)(ws + 786432 * 2 + 4096); // 4 MiB slots
  ushort* s1    = s0 + Tt;
  ushort* s2    = s1 + Tt;
  ushort* s3    = s2 + Tt;
  float*  xsk   = (float*)(s3 + Tt);                 // fp32, 8 MiB
  ushort* xn2   = (ushort*)(xsk + Tt);               // bf16, 4 MiB
  ushort* xn1   = s0;          // dead after QKV
  ushort* qb    = s1;          // q|k|v contiguous: base for fused epilogue
  ushort* attn  = s0;          // dead after Wo
  ushort* hid   = s0;          // [8192,1024] bf16 = 16 MiB spans s0..s3
  float*  outp  = (float*)d_out;

  const dim3 blk(256);
  hipLaunchKernelGGL(prep_kernel, dim3(769), blk, 0, stream,
                     Wq, Wk, Wv, Wo, W1, W2, bq, bk, bv, wt, bqkv);
  hipLaunchKernelGGL(ln_kernel, dim3(MT / 4), blk, 0, stream, x, xn1);

  hipLaunchKernelGGL((gemm_epi<0>), dim3(12, 64), blk, 0, stream,
                     xn1, wtqkv, bqkv, (const void*)nullptr, (void*)qb, 768, Dd);

  hipLaunchKernelGGL(attn_kernel, dim3(Nn / 64, Bb * Hh), blk, 0, stream, s1, s2, s3, attn);

  hipLaunchKernelGGL((gemm_epi<1>), dim3(4, 64), blk, 0, stream,
                     attn, wto, bo, (const void*)x, (void*)xsk, Dd, Dd);
  hipLaunchKernelGGL(ln_kernel, dim3(MT / 4), blk, 0, stream, xsk, xn2);

  hipLaunchKernelGGL((gemm_epi<2>), dim3(16, 64), blk, 0, stream,
                     xn2, wt1, b1, (const void*)nullptr, (void*)hid, DFFd, Dd);
  hipLaunchKernelGGL((gemm_epi<1>), dim3(4, 64), blk, 0, stream,
                     hid, wt2, b2, (const void*)xsk, (void*)outp, Dd, DFFd);
}